// Round 5
// baseline (155.766 us; speedup 1.0000x reference)
//
#include <hip/hip_runtime.h>
#include <hip/hip_bf16.h>
#include <stdint.h>

typedef __attribute__((ext_vector_type(4))) int i32x4;

static constexpr long M_ = 16384;   // 4*4096 rows of x
static constexpr long N_ = 2048;    // out_features
static constexpr long K_ = 2048;    // in_features

// ---- 256x256 8-phase i8 GEMM ----
// BM=BN=256, BK=128 i8. 8 waves (2M x 4N), 512 threads.
// LDS: [isb(A/B)][buf][ks][256 rows][64 B] = 128 KiB dynamic.
// Swizzle: row r, logical 16B-chunk c stored at physical chunk c ^ ((r>>1)&3).
// sched_barrier(0) pins ds_read issue BEFORE the s_barrier (raw s_barrier is
// not a compiler fence; without the pin the scheduler sinks reads past it,
// serializing the CU-wide LDS window against the MFMA window).

#define GLOAD_LDS16(g, l)                                                          \
  __builtin_amdgcn_global_load_lds(                                               \
      (const __attribute__((address_space(1))) unsigned int*)(g),                 \
      (__attribute__((address_space(3))) unsigned int*)(l), 16, 0, 0)

// ---------------- fused stats: max|x| (blocks 0..2047), sum|W| (2048..2559) ----
__global__ __launch_bounds__(256) void k_stats(const float4* __restrict__ x,
                                               const float4* __restrict__ w,
                                               unsigned* __restrict__ gx_bits,
                                               double* __restrict__ gw_sum) {
  const int b = blockIdx.x;
  const int lane = threadIdx.x & 63, wv = threadIdx.x >> 6;
  if (b < 2048) {
    const long S = 524288;
    long i = (long)b * 256 + threadIdx.x;
    float m0 = 0.f, m1 = 0.f;
#pragma unroll
    for (int it = 0; it < 8; ++it) {
      float4 v0 = x[i];
      float4 v1 = x[i + S];
      m0 = fmaxf(m0, fmaxf(fmaxf(fabsf(v0.x), fabsf(v0.y)), fmaxf(fabsf(v0.z), fabsf(v0.w))));
      m1 = fmaxf(m1, fmaxf(fmaxf(fabsf(v1.x), fabsf(v1.y)), fmaxf(fabsf(v1.z), fabsf(v1.w))));
      i += 2 * S;
    }
    float m = fmaxf(m0, m1);
#pragma unroll
    for (int off = 32; off > 0; off >>= 1) m = fmaxf(m, __shfl_down(m, off));
    __shared__ float sm[4];
    if (lane == 0) sm[wv] = m;
    __syncthreads();
    if (threadIdx.x == 0) {
      float bm = fmaxf(fmaxf(sm[0], sm[1]), fmaxf(sm[2], sm[3]));
      atomicMax(gx_bits, __float_as_uint(bm));  // all >= 0
    }
  } else {
    const long S = 131072;
    long i = (long)(b - 2048) * 256 + threadIdx.x;
    double s = 0.0;
#pragma unroll
    for (int it = 0; it < 8; ++it) {
      float4 v = w[i];
      s += (double)fabsf(v.x) + (double)fabsf(v.y) + (double)fabsf(v.z) + (double)fabsf(v.w);
      i += S;
    }
#pragma unroll
    for (int off = 32; off > 0; off >>= 1) s += __shfl_down(s, off);
    __shared__ double sd[4];
    if (lane == 0) sd[wv] = s;
    __syncthreads();
    if (threadIdx.x == 0) atomicAdd(gw_sum, (sd[0] + sd[1]) + (sd[2] + sd[3]));
  }
}

// ---------------- fused quant: x (blocks 0..2047), W (2048..2559) ----------------
__global__ __launch_bounds__(256) void k_quant(const float4* __restrict__ x,
                                               const float4* __restrict__ w,
                                               char4* __restrict__ xq,
                                               char4* __restrict__ wq,
                                               const unsigned* __restrict__ gx_bits,
                                               const double* __restrict__ gw_sum) {
  const int b = blockIdx.x;
  if (b < 2048) {
    const double gx = (double)fmaxf(__uint_as_float(*gx_bits), 1e-8f);
    const double scale = 127.0 / gx;
    const long S = 524288;
    long i = (long)b * 256 + threadIdx.x;
#pragma unroll
    for (int it = 0; it < 16; ++it) {
      float4 v = x[i];
      char4 o;
      o.x = (signed char)(int)fmin(fmax(rint((double)v.x * scale), -127.0), 127.0);
      o.y = (signed char)(int)fmin(fmax(rint((double)v.y * scale), -127.0), 127.0);
      o.z = (signed char)(int)fmin(fmax(rint((double)v.z * scale), -127.0), 127.0);
      o.w = (signed char)(int)fmin(fmax(rint((double)v.w * scale), -127.0), 127.0);
      xq[i] = o;
      i += S;
    }
  } else {
    const double gw = fmax(*gw_sum * (1.0 / 4194304.0), 1e-8);
    const double inv = 1.0 / gw;
    const long S = 131072;
    long i = (long)(b - 2048) * 256 + threadIdx.x;
#pragma unroll
    for (int it = 0; it < 8; ++it) {
      float4 v = w[i];
      char4 o;
      o.x = (signed char)(int)fmin(fmax(rint((double)v.x * inv), -1.0), 1.0);
      o.y = (signed char)(int)fmin(fmax(rint((double)v.y * inv), -1.0), 1.0);
      o.z = (signed char)(int)fmin(fmax(rint((double)v.z * inv), -1.0), 1.0);
      o.w = (signed char)(int)fmin(fmax(rint((double)v.w * inv), -1.0), 1.0);
      wq[i] = o;
      i += S;
    }
  }
}

// ================= 8-phase GEMM =================

template <int ISB, int BUF, int KS>
__device__ __forceinline__ void stage2(signed char* lds, const signed char* gp, int kb,
                                       int go0, int ldsl0) {
  constexpr int R = ISB * 65536 + BUF * 32768 + KS * 16384;
  GLOAD_LDS16(gp + kb + go0, lds + R + ldsl0);
  GLOAD_LDS16(gp + kb + go0 + 32768, lds + R + ldsl0 + 1024);
}

template <int BUF, int KS, int MH, int SGB, int SGBUF, int SGKS, int VM>
__device__ __forceinline__ void phase(signed char* lds, const signed char* Ap,
                                      const signed char* Bp, int kb,
                                      const signed char* pA, const signed char* pB,
                                      int go0, int ldsl0, i32x4 acc[8][4], i32x4 b4[4]) {
  constexpr int RB = BUF * 32768 + KS * 16384;
  constexpr int RA = RB + MH * 4096;
  i32x4 a4[4];
  if (MH == 0) {
#pragma unroll
    for (int n = 0; n < 4; ++n) b4[n] = *(const i32x4*)(pB + RB + n * 1024);
  }
#pragma unroll
  for (int mm = 0; mm < 4; ++mm) a4[mm] = *(const i32x4*)(pA + RA + mm * 1024);
  __builtin_amdgcn_sched_barrier(0);  // pin ds_read issue before the barrier

  if (SGB)
    stage2<1, SGBUF, SGKS>(lds, Bp, kb, go0, ldsl0);
  else
    stage2<0, SGBUF, SGKS>(lds, Ap, kb, go0, ldsl0);
  __builtin_amdgcn_sched_barrier(0);  // pin stage issue before the barrier

  __builtin_amdgcn_s_barrier();
  asm volatile("s_waitcnt lgkmcnt(0)" ::: "memory");
  __builtin_amdgcn_sched_barrier(0);  // rule #18: no MFMA hoisting above the wait
  __builtin_amdgcn_s_setprio(1);
#pragma unroll
  for (int mm = 0; mm < 4; ++mm)
#pragma unroll
    for (int n = 0; n < 4; ++n)
      acc[MH * 4 + mm][n] =
          __builtin_amdgcn_mfma_i32_16x16x64_i8(a4[mm], b4[n], acc[MH * 4 + mm][n], 0, 0, 0);
  __builtin_amdgcn_s_setprio(0);
  if (VM) asm volatile("s_waitcnt vmcnt(8)" ::: "memory");
  __builtin_amdgcn_s_barrier();
}

__global__ __launch_bounds__(512, 2) void k_gemm(
    const signed char* __restrict__ Aq, const signed char* __restrict__ Bq,
    const float* __restrict__ bias, float* __restrict__ out,
    const unsigned* __restrict__ gx_bits, const double* __restrict__ gw_sum) {
  extern __shared__ signed char lds[];

  const int tid = threadIdx.x;
  const int lane = tid & 63;
  const int wid = tid >> 6;
  const int wave_m = wid >> 2;  // 0..1
  const int wave_n = wid & 3;   // 0..3
  const int l15 = lane & 15;

  // XCD swizzle: nwg = 512, 8 XCDs, 64 contiguous work-ids per XCD
  const int wg = (int)((blockIdx.x & 7) * 64 + (blockIdx.x >> 3));
  const int nblk = wg & 7;   // N_/256 = 8
  const int mblk = wg >> 3;  // 0..63
  const long brow = (long)mblk * 256;
  const long bcol = (long)nblk * 256;

  const signed char* Ap = Aq + brow * K_;
  const signed char* Bp = Bq + bcol * K_;

  // precomputed LDS read bases (per-thread constants)
  const int swz = ((lane >> 4) ^ ((l15 >> 1) & 3)) << 4;
  const signed char* pA = lds + (wave_m * 128 + l15) * 64 + swz;
  const signed char* pB = lds + 65536 + (wave_n * 64 + l15) * 64 + swz;

  // stage offsets: slot0 = wid*2, row r0 = wid*32 + (lane>>2),
  // logical chunk c0 = (lane&3) ^ ((lane>>3)&3)
  const int c0 = (lane & 3) ^ ((lane >> 3) & 3);
  const int go0 = (wid * 32 + (lane >> 2)) * (int)K_ + c0 * 16;
  const int ldsl0 = wid * 2048;  // slot0*1024

  i32x4 acc[8][4];
#pragma unroll
  for (int m = 0; m < 8; m++)
#pragma unroll
    for (int n = 0; n < 4; n++) acc[m][n] = (i32x4){0, 0, 0, 0};
  i32x4 b4[4];

  // prologue: tile0 (buf0) both halves, tile1 (buf1) ks0
  stage2<0, 0, 0>(lds, Ap, 0, go0, ldsl0);
  stage2<1, 0, 0>(lds, Bp, 0, go0, ldsl0);
  stage2<0, 0, 1>(lds, Ap, 64, go0, ldsl0);
  stage2<1, 0, 1>(lds, Bp, 64, go0, ldsl0);
  stage2<0, 1, 0>(lds, Ap, 128, go0, ldsl0);
  stage2<1, 1, 0>(lds, Bp, 128, go0, ldsl0);
  asm volatile("s_waitcnt vmcnt(0)" ::: "memory");
  __builtin_amdgcn_s_barrier();

  for (int kt = 0; kt < (int)K_; kt += 256) {
    const int k1h = (kt + 192) & 2047;  // tile t+1, ks1
    const int k2 = (kt + 256) & 2047;   // tile t+2
    const int k3 = (kt + 384) & 2047;   // tile t+3 (wraps harmlessly at the end)
    phase<0, 0, 0, 0, 1, 1, 0>(lds, Ap, Bp, k1h, pA, pB, go0, ldsl0, acc, b4);
    phase<0, 0, 1, 1, 1, 1, 1>(lds, Ap, Bp, k1h, pA, pB, go0, ldsl0, acc, b4);
    phase<0, 1, 0, 0, 0, 0, 0>(lds, Ap, Bp, k2, pA, pB, go0, ldsl0, acc, b4);
    phase<0, 1, 1, 1, 0, 0, 1>(lds, Ap, Bp, k2, pA, pB, go0, ldsl0, acc, b4);
    phase<1, 0, 0, 0, 0, 1, 0>(lds, Ap, Bp, k2 + 64, pA, pB, go0, ldsl0, acc, b4);
    phase<1, 0, 1, 1, 0, 1, 1>(lds, Ap, Bp, k2 + 64, pA, pB, go0, ldsl0, acc, b4);
    phase<1, 1, 0, 0, 1, 0, 0>(lds, Ap, Bp, k3, pA, pB, go0, ldsl0, acc, b4);
    phase<1, 1, 1, 1, 1, 0, 1>(lds, Ap, Bp, k3, pA, pB, go0, ldsl0, acc, b4);
  }

  const float gxf = fmaxf(__uint_as_float(*gx_bits), 1e-8f);
  const double gwd = fmax(*gw_sum * (1.0 / 4194304.0), 1e-8);
  const float alpha = (float)((double)gxf * gwd * (1.0 / 127.0));

#pragma unroll
  for (int n = 0; n < 4; ++n) {
    const long col = bcol + wave_n * 64 + n * 16 + l15;
    const float bv = bias[col];
#pragma unroll
    for (int m = 0; m < 8; ++m) {
      const long row0 = brow + wave_m * 128 + m * 16 + (lane >> 4) * 4;
#pragma unroll
      for (int r = 0; r < 4; ++r) {
        out[(row0 + r) * N_ + col] = (float)acc[m][n][r] * alpha + bv;
      }
    }
  }
}

extern "C" void kernel_launch(void* const* d_in, const int* in_sizes, int n_in,
                              void* d_out, int out_size, void* d_ws, size_t ws_size,
                              hipStream_t stream) {
  const float* x = (const float*)d_in[0];
  const float* W = (const float*)d_in[1];
  const float* b = (const float*)d_in[2];
  float* out = (float*)d_out;

  char* ws = (char*)d_ws;
  double* gw_sum = (double*)ws;            // 8 B
  unsigned* gx_bits = (unsigned*)(ws + 8); // 4 B
  signed char* xq = (signed char*)(ws + 256);                            // M*K i8 = 32 MiB
  signed char* wq = (signed char*)(ws + 256 + (size_t)M_ * (size_t)K_);  // N*K i8 = 4 MiB

  static bool attr_set = false;
  if (!attr_set) {
    (void)hipFuncSetAttribute(reinterpret_cast<const void*>(&k_gemm),
                              hipFuncAttributeMaxDynamicSharedMemorySize, 131072);
    attr_set = true;
  }

  hipMemsetAsync(ws, 0, 16, stream);
  hipLaunchKernelGGL(k_stats, dim3(2560), dim3(256), 0, stream,
                     (const float4*)x, (const float4*)W, gx_bits, gw_sum);
  hipLaunchKernelGGL(k_quant, dim3(2560), dim3(256), 0, stream,
                     (const float4*)x, (const float4*)W, (char4*)xq, (char4*)wq,
                     gx_bits, gw_sum);
  hipLaunchKernelGGL(k_gemm, dim3((unsigned)((M_ / 256) * (N_ / 256))), dim3(512),
                     131072, stream, xq, wq, b, out, gx_bits, gw_sum);
}

// Round 6
// 155.704 us; speedup vs baseline: 1.0004x; 1.0004x over previous
//
#include <hip/hip_runtime.h>
#include <hip/hip_bf16.h>
#include <stdint.h>

typedef __attribute__((ext_vector_type(4))) int i32x4;

static constexpr long M_ = 16384;   // 4*4096 rows of x
static constexpr long N_ = 2048;    // out_features
static constexpr long K_ = 2048;    // in_features

// ---- 256x256 i8 GEMM, 4 pair-phases per iter ----
// BM=BN=256, BK=128 i8. 8 waves (2M x 4N), 512 threads.
// LDS: [isb(A/B)][buf][ks][256 rows][64 B] = 128 KiB dynamic.
// Swizzle: row r, logical 16B-chunk c stored at physical chunk c ^ ((r>>1)&3).
// Pair-phase: {issue 12 ds_read_b128 (b4, a-lo, a-hi) | stage A+B of one
// region | barrier | 32 MFMA with compiler-inserted counted lgkmcnt |
// vmcnt(8) | barrier}. Reads of the hi-half + stage writes land under the
// lo-half MFMA window instead of serializing behind a blanket lgkmcnt(0).

#define GLOAD_LDS16(g, l)                                                          \
  __builtin_amdgcn_global_load_lds(                                               \
      (const __attribute__((address_space(1))) unsigned int*)(g),                 \
      (__attribute__((address_space(3))) unsigned int*)(l), 16, 0, 0)

// ---------------- fused stats: max|x| (blocks 0..2047), sum|W| (2048..2559) ----
__global__ __launch_bounds__(256) void k_stats(const float4* __restrict__ x,
                                               const float4* __restrict__ w,
                                               unsigned* __restrict__ gx_bits,
                                               double* __restrict__ gw_sum) {
  const int b = blockIdx.x;
  const int lane = threadIdx.x & 63, wv = threadIdx.x >> 6;
  if (b < 2048) {
    const long S = 524288;
    long i = (long)b * 256 + threadIdx.x;
    float m0 = 0.f, m1 = 0.f;
#pragma unroll
    for (int it = 0; it < 8; ++it) {
      float4 v0 = x[i];
      float4 v1 = x[i + S];
      m0 = fmaxf(m0, fmaxf(fmaxf(fabsf(v0.x), fabsf(v0.y)), fmaxf(fabsf(v0.z), fabsf(v0.w))));
      m1 = fmaxf(m1, fmaxf(fmaxf(fabsf(v1.x), fabsf(v1.y)), fmaxf(fabsf(v1.z), fabsf(v1.w))));
      i += 2 * S;
    }
    float m = fmaxf(m0, m1);
#pragma unroll
    for (int off = 32; off > 0; off >>= 1) m = fmaxf(m, __shfl_down(m, off));
    __shared__ float sm[4];
    if (lane == 0) sm[wv] = m;
    __syncthreads();
    if (threadIdx.x == 0) {
      float bm = fmaxf(fmaxf(sm[0], sm[1]), fmaxf(sm[2], sm[3]));
      atomicMax(gx_bits, __float_as_uint(bm));  // all >= 0
    }
  } else {
    const long S = 131072;
    long i = (long)(b - 2048) * 256 + threadIdx.x;
    double s = 0.0;
#pragma unroll
    for (int it = 0; it < 8; ++it) {
      float4 v = w[i];
      s += (double)fabsf(v.x) + (double)fabsf(v.y) + (double)fabsf(v.z) + (double)fabsf(v.w);
      i += S;
    }
#pragma unroll
    for (int off = 32; off > 0; off >>= 1) s += __shfl_down(s, off);
    __shared__ double sd[4];
    if (lane == 0) sd[wv] = s;
    __syncthreads();
    if (threadIdx.x == 0) atomicAdd(gw_sum, (sd[0] + sd[1]) + (sd[2] + sd[3]));
  }
}

// ---------------- fused quant: x (blocks 0..2047), W (2048..2559) ----------------
__global__ __launch_bounds__(256) void k_quant(const float4* __restrict__ x,
                                               const float4* __restrict__ w,
                                               char4* __restrict__ xq,
                                               char4* __restrict__ wq,
                                               const unsigned* __restrict__ gx_bits,
                                               const double* __restrict__ gw_sum) {
  const int b = blockIdx.x;
  if (b < 2048) {
    const double gx = (double)fmaxf(__uint_as_float(*gx_bits), 1e-8f);
    const double scale = 127.0 / gx;
    const long S = 524288;
    long i = (long)b * 256 + threadIdx.x;
#pragma unroll
    for (int it = 0; it < 16; ++it) {
      float4 v = x[i];
      char4 o;
      o.x = (signed char)(int)fmin(fmax(rint((double)v.x * scale), -127.0), 127.0);
      o.y = (signed char)(int)fmin(fmax(rint((double)v.y * scale), -127.0), 127.0);
      o.z = (signed char)(int)fmin(fmax(rint((double)v.z * scale), -127.0), 127.0);
      o.w = (signed char)(int)fmin(fmax(rint((double)v.w * scale), -127.0), 127.0);
      xq[i] = o;
      i += S;
    }
  } else {
    const double gw = fmax(*gw_sum * (1.0 / 4194304.0), 1e-8);
    const double inv = 1.0 / gw;
    const long S = 131072;
    long i = (long)(b - 2048) * 256 + threadIdx.x;
#pragma unroll
    for (int it = 0; it < 8; ++it) {
      float4 v = w[i];
      char4 o;
      o.x = (signed char)(int)fmin(fmax(rint((double)v.x * inv), -1.0), 1.0);
      o.y = (signed char)(int)fmin(fmax(rint((double)v.y * inv), -1.0), 1.0);
      o.z = (signed char)(int)fmin(fmax(rint((double)v.z * inv), -1.0), 1.0);
      o.w = (signed char)(int)fmin(fmax(rint((double)v.w * inv), -1.0), 1.0);
      wq[i] = o;
      i += S;
    }
  }
}

// ================= pair-phase GEMM =================

template <int ISB, int BUF, int KS>
__device__ __forceinline__ void stage2(signed char* lds, const signed char* gp, int kb,
                                       int go0, int ldsl0) {
  constexpr int R = ISB * 65536 + BUF * 32768 + KS * 16384;
  GLOAD_LDS16(gp + kb + go0, lds + R + ldsl0);
  GLOAD_LDS16(gp + kb + go0 + 32768, lds + R + ldsl0 + 1024);
}

template <int BUF, int KS, int SGBUF, int SGKS>
__device__ __forceinline__ void pairphase(signed char* lds, const signed char* Ap,
                                          const signed char* Bp, int kb,
                                          const signed char* pA, const signed char* pB,
                                          int go0, int ldsl0, i32x4 acc[8][4]) {
  constexpr int RB = BUF * 32768 + KS * 16384;
  i32x4 b4[4], alo[4], ahi[4];
  // issue order matters: MFMA-lo's operands first, a-hi last (stays outstanding)
#pragma unroll
  for (int n = 0; n < 4; ++n) b4[n] = *(const i32x4*)(pB + RB + n * 1024);
#pragma unroll
  for (int m = 0; m < 4; ++m) alo[m] = *(const i32x4*)(pA + RB + m * 1024);
#pragma unroll
  for (int m = 0; m < 4; ++m) ahi[m] = *(const i32x4*)(pA + RB + 4096 + m * 1024);

  stage2<0, SGBUF, SGKS>(lds, Ap, kb, go0, ldsl0);
  stage2<1, SGBUF, SGKS>(lds, Bp, kb, go0, ldsl0);

  __builtin_amdgcn_s_barrier();
  // no blanket lgkmcnt(0): compiler inserts fine-grained counted lgkmcnt so
  // a-hi reads + stage LDS-writes are serviced under the MFMA-lo window
  __builtin_amdgcn_s_setprio(1);
#pragma unroll
  for (int m = 0; m < 4; ++m)
#pragma unroll
    for (int n = 0; n < 4; ++n)
      acc[m][n] = __builtin_amdgcn_mfma_i32_16x16x64_i8(alo[m], b4[n], acc[m][n], 0, 0, 0);
#pragma unroll
  for (int m = 0; m < 4; ++m)
#pragma unroll
    for (int n = 0; n < 4; ++n)
      acc[4 + m][n] =
          __builtin_amdgcn_mfma_i32_16x16x64_i8(ahi[m], b4[n], acc[4 + m][n], 0, 0, 0);
  __builtin_amdgcn_s_setprio(0);
  asm volatile("s_waitcnt vmcnt(8)" ::: "memory");
  __builtin_amdgcn_s_barrier();
  __builtin_amdgcn_sched_barrier(0);  // nothing crosses the pair boundary upward
}

__global__ __launch_bounds__(512, 2) void k_gemm(
    const signed char* __restrict__ Aq, const signed char* __restrict__ Bq,
    const float* __restrict__ bias, float* __restrict__ out,
    const unsigned* __restrict__ gx_bits, const double* __restrict__ gw_sum) {
  extern __shared__ signed char lds[];

  const int tid = threadIdx.x;
  const int lane = tid & 63;
  const int wid = tid >> 6;
  const int wave_m = wid >> 2;  // 0..1
  const int wave_n = wid & 3;   // 0..3
  const int l15 = lane & 15;

  // XCD swizzle: nwg = 512, 8 XCDs, 64 contiguous work-ids per XCD
  const int wg = (int)((blockIdx.x & 7) * 64 + (blockIdx.x >> 3));
  const int nblk = wg & 7;   // N_/256 = 8
  const int mblk = wg >> 3;  // 0..63
  const long brow = (long)mblk * 256;
  const long bcol = (long)nblk * 256;

  const signed char* Ap = Aq + brow * K_;
  const signed char* Bp = Bq + bcol * K_;

  // precomputed LDS read bases (per-thread constants); all row bases are
  // multiples of 16 -> swizzle depends only on lane&15
  const int swz = ((lane >> 4) ^ ((l15 >> 1) & 3)) << 4;
  const signed char* pA = lds + (wave_m * 128 + l15) * 64 + swz;
  const signed char* pB = lds + 65536 + (wave_n * 64 + l15) * 64 + swz;

  // stage offsets: row r0 = wid*32 + (lane>>2), logical chunk (lane&3)^((lane>>3)&3)
  const int c0 = (lane & 3) ^ ((lane >> 3) & 3);
  const int go0 = (wid * 32 + (lane >> 2)) * (int)K_ + c0 * 16;
  const int ldsl0 = wid * 2048;

  i32x4 acc[8][4];
#pragma unroll
  for (int m = 0; m < 8; m++)
#pragma unroll
    for (int n = 0; n < 4; n++) acc[m][n] = (i32x4){0, 0, 0, 0};

  // prologue: tile0 (buf0) both halves, tile1 (buf1) ks0
  stage2<0, 0, 0>(lds, Ap, 0, go0, ldsl0);
  stage2<1, 0, 0>(lds, Bp, 0, go0, ldsl0);
  stage2<0, 0, 1>(lds, Ap, 64, go0, ldsl0);
  stage2<1, 0, 1>(lds, Bp, 64, go0, ldsl0);
  stage2<0, 1, 0>(lds, Ap, 128, go0, ldsl0);
  stage2<1, 1, 0>(lds, Bp, 128, go0, ldsl0);
  asm volatile("s_waitcnt vmcnt(0)" ::: "memory");
  __builtin_amdgcn_s_barrier();

  for (int kt = 0; kt < (int)K_; kt += 256) {
    const int k1h = (kt + 192) & 2047;  // tile t+1, ks1
    const int k2 = (kt + 256) & 2047;   // tile t+2
    const int k3 = (kt + 384) & 2047;   // tile t+3 (wraps harmlessly at the end)
    pairphase<0, 0, 1, 1>(lds, Ap, Bp, k1h, pA, pB, go0, ldsl0, acc);
    pairphase<0, 1, 0, 0>(lds, Ap, Bp, k2, pA, pB, go0, ldsl0, acc);
    pairphase<1, 0, 0, 1>(lds, Ap, Bp, k2 + 64, pA, pB, go0, ldsl0, acc);
    pairphase<1, 1, 1, 0>(lds, Ap, Bp, k3, pA, pB, go0, ldsl0, acc);
  }

  const float gxf = fmaxf(__uint_as_float(*gx_bits), 1e-8f);
  const double gwd = fmax(*gw_sum * (1.0 / 4194304.0), 1e-8);
  const float alpha = (float)((double)gxf * gwd * (1.0 / 127.0));

#pragma unroll
  for (int n = 0; n < 4; ++n) {
    const long col = bcol + wave_n * 64 + n * 16 + l15;
    const float bv = bias[col];
#pragma unroll
    for (int m = 0; m < 8; ++m) {
      const long row0 = brow + wave_m * 128 + m * 16 + (lane >> 4) * 4;
#pragma unroll
      for (int r = 0; r < 4; ++r) {
        out[(row0 + r) * N_ + col] = (float)acc[m][n][r] * alpha + bv;
      }
    }
  }
}

extern "C" void kernel_launch(void* const* d_in, const int* in_sizes, int n_in,
                              void* d_out, int out_size, void* d_ws, size_t ws_size,
                              hipStream_t stream) {
  const float* x = (const float*)d_in[0];
  const float* W = (const float*)d_in[1];
  const float* b = (const float*)d_in[2];
  float* out = (float*)d_out;

  char* ws = (char*)d_ws;
  double* gw_sum = (double*)ws;            // 8 B
  unsigned* gx_bits = (unsigned*)(ws + 8); // 4 B
  signed char* xq = (signed char*)(ws + 256);                            // M*K i8 = 32 MiB
  signed char* wq = (signed char*)(ws + 256 + (size_t)M_ * (size_t)K_);  // N*K i8 = 4 MiB

  static bool attr_set = false;
  if (!attr_set) {
    (void)hipFuncSetAttribute(reinterpret_cast<const void*>(&k_gemm),
                              hipFuncAttributeMaxDynamicSharedMemorySize, 131072);
    attr_set = true;
  }

  hipMemsetAsync(ws, 0, 16, stream);
  hipLaunchKernelGGL(k_stats, dim3(2560), dim3(256), 0, stream,
                     (const float4*)x, (const float4*)W, gx_bits, gw_sum);
  hipLaunchKernelGGL(k_quant, dim3(2560), dim3(256), 0, stream,
                     (const float4*)x, (const float4*)W, (char4*)xq, (char4*)wq,
                     gx_bits, gw_sum);
  hipLaunchKernelGGL(k_gemm, dim3((unsigned)((M_ / 256) * (N_ / 256))), dim3(512),
                     131072, stream, xq, wq, b, out, gx_bits, gw_sum);
}